// Round 11
// baseline (1647.973 us; speedup 1.0000x reference)
//
#include <hip/hip_runtime.h>

typedef _Float16 f16;
typedef _Float16 h2 __attribute__((ext_vector_type(2)));
typedef _Float16 h8 __attribute__((ext_vector_type(8)));
typedef _Float16 v8h __attribute__((ext_vector_type(8)));
typedef _Float16 v4h __attribute__((ext_vector_type(4)));
typedef float    f4 __attribute__((ext_vector_type(4)));
typedef float    v4f __attribute__((ext_vector_type(4)));
typedef float    f2 __attribute__((ext_vector_type(2)));

#define S_  256
#define B_  1024
#define D_  64
#define H_  128
#define Z_  32
#define BD_ (B_*D_)
#define NSTEP 514

// lgkm-only barrier (global loads stay in flight)
#define BAR() do { \
  asm volatile("s_waitcnt lgkmcnt(0)" ::: "memory"); \
  __builtin_amdgcn_s_barrier(); \
} while (0)

__device__ __forceinline__ h8 cvt8(f4 a, f4 b) {
  h8 w;
  w[0]=(f16)a[0]; w[1]=(f16)a[1]; w[2]=(f16)a[2]; w[3]=(f16)a[3];
  w[4]=(f16)b[0]; w[5]=(f16)b[1]; w[6]=(f16)b[2]; w[7]=(f16)b[3];
  return w;
}

__device__ __forceinline__ h8 ld8(const float* p) {   // 32B-aligned src
  f4 a = *(const f4*)p;
  f4 b = *(const f4*)(p + 4);
  return cvt8(a, b);
}

__device__ __forceinline__ float sigm(float x) { return 1.f / (1.f + __expf(-x)); }
__device__ __forceinline__ float tanh_(float x) {
  float e = __expf(-2.f * fabsf(x));
  float t = (1.f - e) / (1.f + e);
  return copysignf(t, x);
}

// ---------------------------------------------------------------------------
// GRU round-11: 2 batch-tiles per block, interleaved IN-THREAD (deterministic
// ILP: tile B's chains issue while tile A's ds_read/MFMA-dep/exp latency
// drains — the ~57% stall budget diagnosed at r10). 32 blocks x 4 waves.
// Weights SHARED across tiles (zero extra weight regs); raw-f4 xs loads and
// split chains kept from r10. One barrier/step.
// ---------------------------------------------------------------------------
__global__ __launch_bounds__(256, 1) void gru_mfma_kernel(
    const float* __restrict__ xs, const float* __restrict__ Wih,
    const float* __restrict__ Whh, const float* __restrict__ bih,
    const float* __restrict__ bhh, float* __restrict__ hT)
{
  __shared__ f16 hB[2][2][16][136];   // [buf][tile][batch][h + pad8]

  const int t    = threadIdx.x;
  const int wid  = t >> 6;
  const int lane = t & 63;
  const int lr = lane & 15;        // A row / batch col
  const int lg = lane >> 4;        // k-group / C row-group
  const int r0 = blockIdx.x * 32;

  // ---- weight A-frags (shared by both tiles)
  v8h whhR[2][4], whhZ[2][4], whhN[2][4];
  v8h wihR[2][2], wihZ[2][2], wihN[2][2];
  #pragma unroll
  for (int tt = 0; tt < 2; ++tt) {
    const int nr = wid*32 + tt*16 + lr;
    #pragma unroll
    for (int ks = 0; ks < 4; ++ks) {
      whhR[tt][ks] = ld8(Whh + (      nr)*H_ + ks*32 + lg*8);
      whhZ[tt][ks] = ld8(Whh + (128 + nr)*H_ + ks*32 + lg*8);
      whhN[tt][ks] = ld8(Whh + (256 + nr)*H_ + ks*32 + lg*8);
    }
    #pragma unroll
    for (int ks = 0; ks < 2; ++ks) {
      wihR[tt][ks] = ld8(Wih + (      nr)*D_ + ks*32 + lg*8);
      wihZ[tt][ks] = ld8(Wih + (128 + nr)*D_ + ks*32 + lg*8);
      wihN[tt][ks] = ld8(Wih + (256 + nr)*D_ + ks*32 + lg*8);
    }
  }
  v4f birh[2], bizh[2], binv[2], bhnv[2];
  #pragma unroll
  for (int tt = 0; tt < 2; ++tt) {
    const int nb = wid*32 + tt*16 + lg*4;
    v4f a = *(const v4f*)&bih[nb],     b = *(const v4f*)&bhh[nb];
    v4f c = *(const v4f*)&bih[128+nb], d = *(const v4f*)&bhh[128+nb];
    birh[tt] = a + b;
    bizh[tt] = c + d;
    binv[tt] = *(const v4f*)&bih[256+nb];
    bhnv[tt] = *(const v4f*)&bhh[256+nb];
  }

  for (int i = t; i < 2*16*136; i += 256) ((f16*)hB[0])[i] = (f16)0.f;
  v4f hm[2][2] = { { {0.f,0.f,0.f,0.f}, {0.f,0.f,0.f,0.f} },
                   { {0.f,0.f,0.f,0.f}, {0.f,0.f,0.f,0.f} } };  // [u][tt]
  const v4f zero4 = {0.f, 0.f, 0.f, 0.f};

  v8h bx0[2], bx1[2];
  #pragma unroll
  for (int u = 0; u < 2; ++u) {
    bx0[u] = ld8(xs + (S_-1)*BD_ + (r0+u*16+lr)*D_ + lg*8);
    bx1[u] = ld8(xs + (S_-1)*BD_ + (r0+u*16+lr)*D_ + 32 + lg*8);
  }
  __syncthreads();

  int p = 0;
  #pragma unroll 1
  for (int s = 0; s < S_; ++s) {
    // raw next-step loads for both tiles (cvt at iteration end)
    f4 ra0[2], rb0[2], ra1[2], rb1[2];
    const bool have = (s < S_-1);
    #pragma unroll
    for (int u = 0; u < 2; ++u) {
      ra0[u] = zero4; rb0[u] = zero4; ra1[u] = zero4; rb1[u] = zero4;
      if (have) {
        const float* xp = xs + (S_-2-s)*BD_ + (r0+u*16+lr)*D_;
        ra0[u] = *(const f4*)(xp + lg*8);
        rb0[u] = *(const f4*)(xp + lg*8 + 4);
        ra1[u] = *(const f4*)(xp + 32 + lg*8);
        rb1[u] = *(const f4*)(xp + 32 + lg*8 + 4);
      }
    }
    v8h bh[2][4];
    #pragma unroll
    for (int u = 0; u < 2; ++u)
      #pragma unroll
      for (int ks = 0; ks < 4; ++ks)
        bh[u][ks] = *(const v8h*)&hB[p][u][lr][ks*32 + lg*8];

    #pragma unroll
    for (int tt = 0; tt < 2; ++tt) {
      #pragma unroll
      for (int u = 0; u < 2; ++u) {
        v4f ri  = __builtin_amdgcn_mfma_f32_16x16x32_f16(wihR[tt][0], bx0[u], zero4, 0,0,0);
        v4f zi  = __builtin_amdgcn_mfma_f32_16x16x32_f16(wihZ[tt][0], bx0[u], zero4, 0,0,0);
        v4f anx = __builtin_amdgcn_mfma_f32_16x16x32_f16(wihN[tt][0], bx0[u], zero4, 0,0,0);
        ri  = __builtin_amdgcn_mfma_f32_16x16x32_f16(wihR[tt][1], bx1[u], ri,  0,0,0);
        zi  = __builtin_amdgcn_mfma_f32_16x16x32_f16(wihZ[tt][1], bx1[u], zi,  0,0,0);
        anx = __builtin_amdgcn_mfma_f32_16x16x32_f16(wihN[tt][1], bx1[u], anx, 0,0,0);
        v4f rh = zero4, zh = zero4, anh = zero4;
        #pragma unroll
        for (int ks = 0; ks < 4; ++ks) {
          rh  = __builtin_amdgcn_mfma_f32_16x16x32_f16(whhR[tt][ks], bh[u][ks], rh,  0,0,0);
          zh  = __builtin_amdgcn_mfma_f32_16x16x32_f16(whhZ[tt][ks], bh[u][ks], zh,  0,0,0);
          anh = __builtin_amdgcn_mfma_f32_16x16x32_f16(whhN[tt][ks], bh[u][ks], anh, 0,0,0);
        }
        v4h o;
        #pragma unroll
        for (int i = 0; i < 4; ++i) {
          float r  = sigm(ri[i] + rh[i] + birh[tt][i]);
          float zg = sigm(zi[i] + zh[i] + bizh[tt][i]);
          float n  = tanh_(anx[i] + binv[tt][i] + r*(anh[i] + bhnv[tt][i]));
          hm[u][tt][i] = (1.f - zg)*n + zg*hm[u][tt][i];
          o[i] = (f16)hm[u][tt][i];
        }
        *(v4h*)&hB[p^1][u][lr][wid*32 + tt*16 + lg*4] = o;
      }
    }
    BAR();
    if (have) {
      #pragma unroll
      for (int u = 0; u < 2; ++u) {
        bx0[u] = cvt8(ra0[u], rb0[u]);
        bx1[u] = cvt8(ra1[u], rb1[u]);
      }
    }
    p ^= 1;
  }

  #pragma unroll
  for (int u = 0; u < 2; ++u)
    #pragma unroll
    for (int tt = 0; tt < 2; ++tt)
      *(v4f*)&hT[(r0+u*16+lr)*H_ + wid*32 + tt*16 + lg*4] = hm[u][tt];
}

// ---------------------------------------------------------------------------
// Encoder head (unchanged; tiny): 256 blocks x 4 rows.
// ---------------------------------------------------------------------------
__global__ __launch_bounds__(256) void enc_kernel(
    const float* __restrict__ hT, const float* __restrict__ encW,
    const float* __restrict__ encB, const float* __restrict__ qW,
    const float* __restrict__ qB, const float* __restrict__ eps,
    const float* __restrict__ pm, const float* __restrict__ pls,
    float* __restrict__ z0, float* __restrict__ out)
{
  __shared__ float hTl[4][128];
  __shared__ float ctx[4][64];
  __shared__ float ql[4][64];
  const int t = threadIdx.x;
  const int b0 = blockIdx.x * 4;
  const int lb = t >> 6, j = t & 63;

  for (int i = t; i < 512; i += 256) hTl[i>>7][i&127] = hT[b0*H_ + i];
  __syncthreads();

  float acc = encB[j];
  #pragma unroll
  for (int k = 0; k < 128; k += 4) {
    f4 w = *(const f4*)&encW[j*128 + k];
    acc += hTl[lb][k]*w[0] + hTl[lb][k+1]*w[1] + hTl[lb][k+2]*w[2] + hTl[lb][k+3]*w[3];
  }
  ctx[lb][j] = acc;
  __syncthreads();

  float q = qB[j];
  #pragma unroll
  for (int k = 0; k < 64; k += 4) {
    f4 w = *(const f4*)&qW[j*64 + k];
    q += ctx[lb][k]*w[0] + ctx[lb][k+1]*w[1] + ctx[lb][k+2]*w[2] + ctx[lb][k+3]*w[3];
  }
  ql[lb][j] = q;
  __syncthreads();

  float kl = 0.f;
  if (j < 32) {
    float mean = ql[lb][j], ls = ql[lb][j+32];
    z0[(b0+lb)*Z_ + j] = mean + __expf(ls)*eps[(b0+lb)*Z_ + j];
    float pmj = pm[j], plsj = pls[j];
    float dm = mean - pmj;
    kl = plsj - ls + (__expf(2.f*ls) + dm*dm) / (2.f*__expf(2.f*plsj)) - 0.5f;
  }
  #pragma unroll
  for (int s2 = 32; s2 > 0; s2 >>= 1) kl += __shfl_down(kl, s2, 64);
  if (j == 0) atomicAdd(out + 1, kl * (1.f/1024.f));
}

// ---------------------------------------------------------------------------
// SDE round-11: r10 structure x 2 batch-tiles per block (32 blocks).
// Tiles interleaved in-thread in G1/G2/proj; phase-3 maps the 4 (tile x
// z-half) drift+diff jobs 1:1 onto the 4 waves (tw=wid>>1, wz=wid&1) —
// waves 2,3 no longer idle there. Weights shared; proj-hoist + chain
// splits kept from r10.
// ---------------------------------------------------------------------------
__global__ __launch_bounds__(256, 1) void sde_mfma_kernel(
    const float* __restrict__ z0, const float* __restrict__ ts,
    const float* __restrict__ dW, const float* __restrict__ xs,
    const float* __restrict__ fW1, const float* __restrict__ fb1,
    const float* __restrict__ fW2, const float* __restrict__ fb2,
    const float* __restrict__ fW3, const float* __restrict__ fb3,
    const float* __restrict__ gW1, const float* __restrict__ gb1,
    const float* __restrict__ gW2, const float* __restrict__ gb2,
    const float* __restrict__ pW, const float* __restrict__ pb,
    float* __restrict__ out)
{
  __shared__ f16 Xa[2][16*72];     // per tile: 0..31 z, 32 t, 33 one, 34 t-resid
  __shared__ f16 h1A[2][16*168];
  __shared__ f16 ghA[2][16*168];
  __shared__ f16 h2A[2][16*168];
  __shared__ float tsL[516];
  __shared__ float lred[4];

  const int t    = threadIdx.x;
  const int wid  = t >> 6;
  const int lane = t & 63;
  const int lr = lane & 15;       // tile-row (A) / batch-col (B/C)
  const int lg = lane >> 4;       // k-group / C row-group
  const int r0 = blockIdx.x * 32;
  const int wz = wid & 1;         // z-half (phase 3)
  const int tw = wid >> 1;        // batch-tile (phase 3)

  // ---- stage W1pad (K=64): 4 tiles/wave -> 8 frags
  v8h w1r[8];
  #pragma unroll
  for (int nl = 0; nl < 4; ++nl) {
    const int n = wid*4 + nl;
    const float* src = (n < 8) ? (fW1 + (n*16+lr)*33) : (gW1 + ((n-8)*16+lr)*33);
    const float bsv  = (n < 8) ? fb1[n*16+lr] : gb1[(n-8)*16+lr];
    #pragma unroll
    for (int ks = 0; ks < 2; ++ks) {
      v8h w;
      #pragma unroll
      for (int j = 0; j < 8; ++j) {
        const int kp = ks*32 + lg*8 + j;
        float v;
        if (kp < 32)                   v = src[1+kp];
        else if (kp == 32 || kp == 34) v = src[0];
        else if (kp == 33)             v = bsv;
        else                           v = 0.f;
        w[j] = (f16)v;
      }
      w1r[nl*2+ks] = w;
    }
  }
  // ---- stage W2pad (K=160): 2 tiles/wave -> 10 frags
  v8h w2r[10];
  #pragma unroll
  for (int nl = 0; nl < 2; ++nl) {
    const int n = wid*2 + nl;
    const float* src = fW2 + (n*16+lr)*128;
    const float bsv = fb2[n*16+lr];
    #pragma unroll
    for (int ks = 0; ks < 5; ++ks) {
      v8h w;
      #pragma unroll
      for (int j = 0; j < 8; ++j) {
        const int kp = ks*32 + lg*8 + j;
        float v = (kp < 128) ? src[kp] : ((kp == 128) ? bsv : 0.f);
        w[j] = (f16)v;
      }
      w2r[nl*5+ks] = w;
    }
  }
  // ---- stage W3 (drift fW3 + diff gW2, K=160), z-half wz: 10 frags
  v8h w3d[5], w3g[5];
  {
    const float* sd = fW3 + (wz*16+lr)*128;
    const float* sg = gW2 + (wz*16+lr)*128;
    const float bd = fb3[wz*16+lr], bg = gb2[wz*16+lr];
    #pragma unroll
    for (int ks = 0; ks < 5; ++ks) {
      v8h wd, wg;
      #pragma unroll
      for (int j = 0; j < 8; ++j) {
        const int kp = ks*32 + lg*8 + j;
        wd[j] = (f16)((kp < 128) ? sd[kp] : ((kp == 128) ? bd : 0.f));
        wg[j] = (f16)((kp < 128) ? sg[kp] : ((kp == 128) ? bg : 0.f));
      }
      w3d[ks] = wd; w3g[ks] = wg;
    }
  }
  // ---- stage pWpad (K=64): 1 tile/wave -> 2 frags
  v8h pwr[2];
  {
    const float* sp = pW + (wid*16+lr)*32;
    const float bp = pb[wid*16+lr];
    #pragma unroll
    for (int ks = 0; ks < 2; ++ks) {
      v8h w;
      #pragma unroll
      for (int j = 0; j < 8; ++j) {
        const int kp = ks*32 + lg*8 + j;
        w[j] = (f16)((kp < 32) ? sp[kp] : ((kp == 33) ? bp : 0.f));
      }
      pwr[ks] = w;
    }
  }

  // ---- init LDS
  for (int i = t; i < 2*16*72; i += 256) ((f16*)Xa[0])[i] = (f16)0.f;
  for (int i = t; i < 2*16*168; i += 256) {
    ((f16*)h1A[0])[i] = (f16)0.f;
    ((f16*)ghA[0])[i] = (f16)0.f;
    ((f16*)h2A[0])[i] = (f16)0.f;
  }
  for (int i = t; i < 515; i += 256) tsL[i] = ts[i];
  __syncthreads();
  if (t < 16) {
    const float t0v = tsL[0];
    const f16 th0 = (f16)t0v;
    #pragma unroll
    for (int u = 0; u < 2; ++u) {
      Xa[u][t*72 + 33] = (f16)1.f;
      h1A[u][t*168 + 128] = (f16)1.f;
      ghA[u][t*168 + 128] = (f16)1.f;
      h2A[u][t*168 + 128] = (f16)1.f;
      Xa[u][t*72 + 32] = th0;
      Xa[u][t*72 + 34] = (f16)(t0v - (float)th0);
    }
  }
  const v4f zero4 = {0.f, 0.f, 0.f, 0.f};
  // z master: ALL 4 waves — wave = (tile tw, z-half wz)
  v4f zm = *(const v4f*)&z0[(r0 + tw*16 + lr)*Z_ + wz*16 + lg*4];
  {
    v4h a;
    #pragma unroll
    for (int i = 0; i < 4; ++i) a[i] = (f16)zm[i];
    *(v4h*)&Xa[tw][lr*72 + wz*16 + lg*4] = a;
  }
  float loss = 0.f;
  bool pev = false, pod = false;   // deferred-proj state (for step l-1)
  int  pln = 0;
  v4f  pxv[2] = {zero4, zero4};
  __syncthreads();

  #pragma unroll 1
  for (int l = 0; l < NSTEP; ++l) {
    const float dt  = tsL[l+1] - tsL[l];
    const float sdt = sqrtf(dt);
    const int ln = l + 1;
    const bool ev = ((ln & 1) == 0) && ln >= 2 && ln <= 512;
    const bool od = ((ln & 1) == 1) && ln >= 3 && ln <= 511;

    // globals: dW consumed at phase3, xs next step (deferred proj)
    v4f dwv = *(const v4f*)&dW[(l*B_ + r0 + tw*16 + lr)*Z_ + wz*16 + lg*4];
    v4f xvl[2] = {zero4, zero4};
    if (ev) {
      #pragma unroll
      for (int u = 0; u < 2; ++u)
        xvl[u] = *(const v4f*)&xs[(((ln-2)>>1)*B_ + r0 + u*16 + lr)*D_ + wid*16 + lg*4];
    }

    // ---- GEMM1 (both tiles) + deferred proj(l-1)
    v4f pj[2] = {zero4, zero4};
    {
      v8h bx0[2], bx1[2];
      #pragma unroll
      for (int u = 0; u < 2; ++u) {
        bx0[u] = *(const v8h*)&Xa[u][lr*72 +  0 + lg*8];
        bx1[u] = *(const v8h*)&Xa[u][lr*72 + 32 + lg*8];
      }
      #pragma unroll
      for (int nl = 0; nl < 4; ++nl) {
        #pragma unroll
        for (int u = 0; u < 2; ++u) {
          v4f acc = __builtin_amdgcn_mfma_f32_16x16x32_f16(w1r[nl*2+0], bx0[u], zero4, 0, 0, 0);
          acc = __builtin_amdgcn_mfma_f32_16x16x32_f16(w1r[nl*2+1], bx1[u], acc, 0, 0, 0);
          v4h o;
          #pragma unroll
          for (int i = 0; i < 4; ++i) o[i] = (f16)fmaxf(acc[i], 0.f);
          if (wid < 2) *(v4h*)&h1A[u][lr*168 + (wid*4+nl)*16 + lg*4] = o;
          else         *(v4h*)&ghA[u][lr*168 + ((wid-2)*4+nl)*16 + lg*4] = o;
        }
      }
      if (pev || pod) {
        #pragma unroll
        for (int u = 0; u < 2; ++u) {
          pj[u] = __builtin_amdgcn_mfma_f32_16x16x32_f16(pwr[0], bx0[u], zero4, 0, 0, 0);
          pj[u] = __builtin_amdgcn_mfma_f32_16x16x32_f16(pwr[1], bx1[u], pj[u], 0, 0, 0);
        }
      }
    }
    BAR();   // B1

    // ---- GEMM2 (both tiles, K-chains split 3+2) + deferred-proj consume
    {
      v8h bh[2][5];
      #pragma unroll
      for (int u = 0; u < 2; ++u)
        #pragma unroll
        for (int ks = 0; ks < 5; ++ks)
          bh[u][ks] = *(const v8h*)&h1A[u][lr*168 + ks*32 + lg*8];
      v4f a0[2][2], a1[2][2];
      #pragma unroll
      for (int nl = 0; nl < 2; ++nl) {
        #pragma unroll
        for (int u = 0; u < 2; ++u) {
          a0[u][nl] = __builtin_amdgcn_mfma_f32_16x16x32_f16(w2r[nl*5+0], bh[u][0], zero4, 0, 0, 0);
          a1[u][nl] = __builtin_amdgcn_mfma_f32_16x16x32_f16(w2r[nl*5+1], bh[u][1], zero4, 0, 0, 0);
          a0[u][nl] = __builtin_amdgcn_mfma_f32_16x16x32_f16(w2r[nl*5+2], bh[u][2], a0[u][nl], 0, 0, 0);
          a1[u][nl] = __builtin_amdgcn_mfma_f32_16x16x32_f16(w2r[nl*5+3], bh[u][3], a1[u][nl], 0, 0, 0);
          a0[u][nl] = __builtin_amdgcn_mfma_f32_16x16x32_f16(w2r[nl*5+4], bh[u][4], a0[u][nl], 0, 0, 0);
        }
      }
      // consume deferred proj while GEMM2 chains are in flight
      if (pev) {
        #pragma unroll
        for (int u = 0; u < 2; ++u)
          #pragma unroll
          for (int i = 0; i < 4; ++i) { float d = pj[u][i] - pxv[u][i]; loss = fmaf(d, d, loss); }
      } else if (pod) {
        #pragma unroll
        for (int u = 0; u < 2; ++u) {
          float* op = out + 2 + (((pln-3)>>1)*B_ + r0 + u*16 + lr)*D_ + wid*16 + lg*4;
          *(f2*)&op[0] = (f2){pj[u][0], pj[u][1]};
          *(f2*)&op[2] = (f2){pj[u][2], pj[u][3]};
        }
      }
      #pragma unroll
      for (int nl = 0; nl < 2; ++nl) {
        #pragma unroll
        for (int u = 0; u < 2; ++u) {
          v4f acc = a0[u][nl] + a1[u][nl];
          v4h o;
          #pragma unroll
          for (int i = 0; i < 4; ++i) o[i] = (f16)fmaxf(acc[i], 0.f);
          *(v4h*)&h2A[u][lr*168 + (wid*2+nl)*16 + lg*4] = o;
        }
      }
    }
    BAR();   // B2

    // ---- phase 3: wave = (tile tw, z-half wz) — all 4 waves busy
    {
      v8h b2f[5], bgf[5];
      #pragma unroll
      for (int ks = 0; ks < 5; ++ks) {
        b2f[ks] = *(const v8h*)&h2A[tw][lr*168 + ks*32 + lg*8];
        bgf[ks] = *(const v8h*)&ghA[tw][lr*168 + ks*32 + lg*8];
      }
      v4f d0 = zero4, d1 = zero4, f0 = zero4, f1 = zero4;
      d0 = __builtin_amdgcn_mfma_f32_16x16x32_f16(w3d[0], b2f[0], d0, 0, 0, 0);
      f0 = __builtin_amdgcn_mfma_f32_16x16x32_f16(w3g[0], bgf[0], f0, 0, 0, 0);
      d1 = __builtin_amdgcn_mfma_f32_16x16x32_f16(w3d[1], b2f[1], d1, 0, 0, 0);
      f1 = __builtin_amdgcn_mfma_f32_16x16x32_f16(w3g[1], bgf[1], f1, 0, 0, 0);
      d0 = __builtin_amdgcn_mfma_f32_16x16x32_f16(w3d[2], b2f[2], d0, 0, 0, 0);
      f0 = __builtin_amdgcn_mfma_f32_16x16x32_f16(w3g[2], bgf[2], f0, 0, 0, 0);
      d1 = __builtin_amdgcn_mfma_f32_16x16x32_f16(w3d[3], b2f[3], d1, 0, 0, 0);
      f1 = __builtin_amdgcn_mfma_f32_16x16x32_f16(w3g[3], bgf[3], f1, 0, 0, 0);
      d0 = __builtin_amdgcn_mfma_f32_16x16x32_f16(w3d[4], b2f[4], d0, 0, 0, 0);
      f0 = __builtin_amdgcn_mfma_f32_16x16x32_f16(w3g[4], bgf[4], f0, 0, 0, 0);
      #pragma unroll
      for (int i = 0; i < 4; ++i)
        zm[i] += (d0[i] + d1[i])*dt + (f0[i] + f1[i])*(sdt*dwv[i]);
      v4h a;
      #pragma unroll
      for (int i = 0; i < 4; ++i) a[i] = (f16)zm[i];
      *(v4h*)&Xa[tw][lr*72 + wz*16 + lg*4] = a;
      if (wz == 0 && lg == 0) {       // waves 0,2: t-cols for own tile
        const float tn = tsL[l+1];
        const f16 th = (f16)tn;
        Xa[tw][lr*72 + 32] = th;
        Xa[tw][lr*72 + 34] = (f16)(tn - (float)th);
      }
    }
    BAR();   // B3

    // hand off proj state to next iteration
    pev = ev; pod = od; pln = ln;
    if (ev) { pxv[0] = xvl[0]; pxv[1] = xvl[1]; }
  }

  #pragma unroll
  for (int s2 = 32; s2 > 0; s2 >>= 1) loss += __shfl_down(loss, s2, 64);
  if (lane == 0) lred[wid] = loss;
  __syncthreads();
  if (t == 0)
    atomicAdd(out + 0, (lred[0] + lred[1] + lred[2] + lred[3]) * (1.f/16777216.f));
}

extern "C" void kernel_launch(void* const* d_in, const int* in_sizes, int n_in,
                              void* d_out, int out_size, void* d_ws, size_t ws_size,
                              hipStream_t stream) {
  (void)in_sizes; (void)n_in; (void)out_size; (void)ws_size;
  const float* xs   = (const float*)d_in[0];
  const float* ts   = (const float*)d_in[1];
  const float* eps  = (const float*)d_in[2];
  const float* dWp  = (const float*)d_in[3];
  const float* Wih  = (const float*)d_in[4];
  const float* Whh  = (const float*)d_in[5];
  const float* bih  = (const float*)d_in[6];
  const float* bhh  = (const float*)d_in[7];
  const float* encW = (const float*)d_in[8];
  const float* encB = (const float*)d_in[9];
  const float* qW   = (const float*)d_in[10];
  const float* qB   = (const float*)d_in[11];
  const float* fW1  = (const float*)d_in[12];
  const float* fb1  = (const float*)d_in[13];
  const float* fW2  = (const float*)d_in[14];
  const float* fb2  = (const float*)d_in[15];
  const float* fW3  = (const float*)d_in[16];
  const float* fb3  = (const float*)d_in[17];
  const float* gW1  = (const float*)d_in[18];
  const float* gb1  = (const float*)d_in[19];
  const float* gW2  = (const float*)d_in[20];
  const float* gb2  = (const float*)d_in[21];
  const float* pW   = (const float*)d_in[22];
  const float* pb   = (const float*)d_in[23];
  const float* pm   = (const float*)d_in[24];
  const float* pls  = (const float*)d_in[25];

  float* out = (float*)d_out;
  float* ws  = (float*)d_ws;
  float* hT = ws;              // 1024*128 floats
  float* z0 = ws + 131072;     // 1024*32 floats

  hipMemsetAsync(d_out, 0, 2*sizeof(float), stream);
  hipLaunchKernelGGL(gru_mfma_kernel, dim3(32), dim3(256), 0, stream,
                     xs, Wih, Whh, bih, bhh, hT);
  hipLaunchKernelGGL(enc_kernel, dim3(256), dim3(256), 0, stream,
                     hT, encW, encB, qW, qB, eps, pm, pls, z0, out);
  hipLaunchKernelGGL(sde_mfma_kernel, dim3(32), dim3(256), 0, stream,
                     z0, ts, dWp, xs, fW1, fb1, fW2, fb2, fW3, fb3,
                     gW1, gb1, gW2, gb2, pW, pb, out);
}